// Round 1
// baseline (1096.285 us; speedup 1.0000x reference)
//
#include <hip/hip_runtime.h>
#include <math.h>

#define NUM_LAYER 6

// ---------------- Pass A: Q = Wq*vf + bq ; K = Wk*ef + bk ----------------
// C = 128 assumed (M == 128 == TILE). 128x128 tile, BK=8, 256 thr, 8x8 micro.
__global__ __launch_bounds__(256) void qk_gemm(
    const float* __restrict__ Wq, const float* __restrict__ bq,
    const float* __restrict__ vf,
    const float* __restrict__ Wk, const float* __restrict__ bk,
    const float* __restrict__ ef,
    float* __restrict__ Qout, float* __restrict__ Kout,
    int C, int N, int bs) {
  int which = (int)blockIdx.y >= bs;
  int b = (int)blockIdx.y - (which ? bs : 0);
  const float* Wm = which ? Wk : Wq;
  const float* bias = which ? bk : bq;
  const float* X = (which ? ef : vf) + (size_t)b * C * N;
  float* P = (which ? Kout : Qout) + (size_t)b * C * N;
  int n0 = blockIdx.x * 128;
  __shared__ float As[8][128];
  __shared__ float Xs[8][128];
  int t = threadIdx.x;
  int tx = t & 15, ty = t >> 4;
  int ao = t >> 1, ac = (t & 1) * 4;      // A staging (transposed)
  int lk = t >> 5, lj = (t & 31) * 4;     // X staging
  float acc[8][8] = {};
  for (int c0 = 0; c0 < C; c0 += 8) {
    __syncthreads();
    float4 wv = *(const float4*)&Wm[(size_t)ao * C + c0 + ac];
    As[ac + 0][ao] = wv.x; As[ac + 1][ao] = wv.y;
    As[ac + 2][ao] = wv.z; As[ac + 3][ao] = wv.w;
    *(float4*)&Xs[lk][lj] = *(const float4*)&X[(size_t)(c0 + lk) * N + n0 + lj];
    __syncthreads();
#pragma unroll
    for (int kk = 0; kk < 8; ++kk) {
      float a[8], bb[8];
      *(float4*)&a[0]  = *(const float4*)&As[kk][ty * 4];
      *(float4*)&a[4]  = *(const float4*)&As[kk][64 + ty * 4];
      *(float4*)&bb[0] = *(const float4*)&Xs[kk][tx * 4];
      *(float4*)&bb[4] = *(const float4*)&Xs[kk][64 + tx * 4];
#pragma unroll
      for (int i = 0; i < 8; ++i)
#pragma unroll
        for (int j = 0; j < 8; ++j)
          acc[i][j] = fmaf(a[i], bb[j], acc[i][j]);
    }
  }
#pragma unroll
  for (int i = 0; i < 8; ++i) {
    int row = (i >> 2) * 64 + ty * 4 + (i & 3);
    float bv = bias[row];
    float4 o0 = { acc[i][0] + bv, acc[i][1] + bv, acc[i][2] + bv, acc[i][3] + bv };
    float4 o1 = { acc[i][4] + bv, acc[i][5] + bv, acc[i][6] + bv, acc[i][7] + bv };
    *(float4*)&P[(size_t)row * N + n0 + tx * 4] = o0;
    *(float4*)&P[(size_t)row * N + n0 + 64 + tx * 4] = o1;
  }
}

// ---------------- Pass B: score = sigmoid(Q^T K / sqrt(dh)) masked ----------------
__global__ __launch_bounds__(256) void att_score(
    const float* __restrict__ Q, const float* __restrict__ K,
    const float* __restrict__ H0, float* __restrict__ score,
    int C, int N, float sdh) {
  int b = blockIdx.z;
  int o0 = blockIdx.y * 128, i0 = blockIdx.x * 128;
  const float* Qb = Q + (size_t)b * C * N;
  const float* Kb = K + (size_t)b * C * N;
  const float* Hb = H0 + (size_t)b * N * N;
  float* Sb = score + (size_t)b * N * N;
  __shared__ float As[8][128];
  __shared__ float Bs[8][128];
  int t = threadIdx.x;
  int tx = t & 15, ty = t >> 4;
  int lk = t >> 5, lj = (t & 31) * 4;
  float acc[8][8] = {};
  for (int c0 = 0; c0 < C; c0 += 8) {
    __syncthreads();
    *(float4*)&As[lk][lj] = *(const float4*)&Qb[(size_t)(c0 + lk) * N + o0 + lj];
    *(float4*)&Bs[lk][lj] = *(const float4*)&Kb[(size_t)(c0 + lk) * N + i0 + lj];
    __syncthreads();
#pragma unroll
    for (int kk = 0; kk < 8; ++kk) {
      float a[8], bb[8];
      *(float4*)&a[0]  = *(const float4*)&As[kk][ty * 4];
      *(float4*)&a[4]  = *(const float4*)&As[kk][64 + ty * 4];
      *(float4*)&bb[0] = *(const float4*)&Bs[kk][tx * 4];
      *(float4*)&bb[4] = *(const float4*)&Bs[kk][64 + tx * 4];
#pragma unroll
      for (int i = 0; i < 8; ++i)
#pragma unroll
        for (int j = 0; j < 8; ++j)
          acc[i][j] = fmaf(a[i], bb[j], acc[i][j]);
    }
  }
#pragma unroll
  for (int i = 0; i < 8; ++i) {
    int row = o0 + (i >> 2) * 64 + ty * 4 + (i & 3);
    size_t base = (size_t)row * N + i0;
#pragma unroll
    for (int g = 0; g < 2; ++g) {
      size_t off = base + g * 64 + tx * 4;
      float4 h = *(const float4*)&Hb[off];
      float s0 = acc[i][g * 4 + 0] / sdh;
      float s1 = acc[i][g * 4 + 1] / sdh;
      float s2 = acc[i][g * 4 + 2] / sdh;
      float s3 = acc[i][g * 4 + 3] / sdh;
      float4 o;
      o.x = (h.x > 0.f) ? 1.f / (1.f + expf(-s0)) : 0.f;
      o.y = (h.y > 0.f) ? 1.f / (1.f + expf(-s1)) : 0.f;
      o.z = (h.z > 0.f) ? 1.f / (1.f + expf(-s2)) : 0.f;
      o.w = (h.w > 0.f) ? 1.f / (1.f + expf(-s3)) : 0.f;
      *(float4*)&Sb[off] = o;
    }
  }
}

// ---------------- Pass C: exact k-th largest per row (bitwise binary search) --------
__global__ __launch_bounds__(256) void topk_thresh(
    const float* __restrict__ score, float* __restrict__ amin,
    const int* __restrict__ itp, int N) {
  int row = blockIdx.x;                  // b*N + o
  const float* s = score + (size_t)row * N;
  int t = threadIdx.x;
  int nq = N >> 8;                       // values per thread (8 @ N=2048)
  float v[16];
  for (int q = 0; q < nq; ++q) v[q] = s[t + (q << 8)];
  int itv = *itp;
  double kx = (double)N * 0.1 * (double)(NUM_LAYER - 1 - itv);
  int k = (int)floor(kx + 0.5);
  __shared__ int part[4];
  unsigned lo = 0u, hi = 0x3F800000u;    // [0, 1.0]; scores are in [0,1]
  while (lo < hi) {
    unsigned mid = lo + ((hi - lo + 1u) >> 1);
    float thr = __uint_as_float(mid);
    int c = 0;
    for (int q = 0; q < nq; ++q) c += (v[q] >= thr) ? 1 : 0;
    for (int off = 32; off; off >>= 1) c += __shfl_down(c, off);
    __syncthreads();
    if ((t & 63) == 0) part[t >> 6] = c;
    __syncthreads();
    int tot = part[0] + part[1] + part[2] + part[3];
    if (tot >= k) lo = mid; else hi = mid - 1u;
  }
  if (t == 0) amin[row] = __uint_as_float(lo);
}

// ---------------- Pass D: W, H, deg_E, deg_V, We (fused) ----------------
// block: 16 rows x N cols; thread t covers cols 4t..4t+3 (+g*1024). N<=4096.
__global__ __launch_bounds__(256) void wh_fused(
    const float* __restrict__ score, const float* __restrict__ H0,
    const float* __restrict__ amin,
    float* __restrict__ Wout, float* __restrict__ Hout,
    float* __restrict__ degE, float* __restrict__ degV, float* __restrict__ We,
    int N) {
  int b = blockIdx.y;
  int r0 = blockIdx.x * 16;
  int t = threadIdx.x;
  int G = N >> 10;
  size_t bNN = (size_t)b * N * N;
  float colH[4][4] = {};
  float colW[4][4] = {};
  __shared__ float part[4][16];
  for (int r = 0; r < 16; ++r) {
    int row = r0 + r;
    float am = amin[b * N + row];
    float rp = 0.f;
    for (int g = 0; g < G; ++g) {
      size_t off = bNN + (size_t)row * N + 4 * t + g * 1024;
      float4 s  = *(const float4*)(score + off);
      float4 h0 = *(const float4*)(H0 + off);
      float4 w, h;
      w.x = (s.x >= am) ? s.x : 0.f; h.x = (w.x > 0.f) ? h0.x : 0.f;
      w.y = (s.y >= am) ? s.y : 0.f; h.y = (w.y > 0.f) ? h0.y : 0.f;
      w.z = (s.z >= am) ? s.z : 0.f; h.z = (w.z > 0.f) ? h0.z : 0.f;
      w.w = (s.w >= am) ? s.w : 0.f; h.w = (w.w > 0.f) ? h0.w : 0.f;
      *(float4*)(Wout + off) = w;
      *(float4*)(Hout + off) = h;
      rp += h.x + h.y + h.z + h.w;
      colH[g][0] += h.x; colH[g][1] += h.y; colH[g][2] += h.z; colH[g][3] += h.w;
      colW[g][0] += w.x; colW[g][1] += w.y; colW[g][2] += w.z; colW[g][3] += w.w;
    }
    for (int off = 32; off; off >>= 1) rp += __shfl_down(rp, off);
    if ((t & 63) == 0) part[t >> 6][r] = rp;
  }
  __syncthreads();
  if (t < 16) degV[b * N + r0 + t] = part[0][t] + part[1][t] + part[2][t] + part[3][t];
  for (int g = 0; g < G; ++g)
    for (int j = 0; j < 4; ++j) {
      atomicAdd(&degE[b * N + 4 * t + g * 1024 + j], colH[g][j]);
      atomicAdd(&We[b * N + 4 * t + g * 1024 + j], colW[g][j]);
    }
}

// ---------------- Pass E: diagonal fill (zeros + 1/deg on diag) ----------------
__global__ __launch_bounds__(256) void diag_fill(
    float* __restrict__ out, const float* __restrict__ deg, int N, int nsh) {
  int b = blockIdx.y;
  size_t per = (size_t)N * N / 4;
  float* ob = out + (size_t)b * N * N;
  const float* db = deg + (size_t)b * N;
  for (size_t f = (size_t)blockIdx.x * blockDim.x + threadIdx.x; f < per;
       f += (size_t)gridDim.x * blockDim.x) {
    size_t idx = f * 4;
    int r = (int)(idx >> nsh);
    int c = (int)(idx & (size_t)(N - 1));
    float4 v = {0.f, 0.f, 0.f, 0.f};
    int d = r - c;
    if (d >= 0 && d < 4) {
      float dg = db[r];
      ((float*)&v)[d] = (dg != 0.f) ? 1.f / dg : 0.f;
    }
    *(float4*)&ob[idx] = v;
  }
}

// ---------------- Pass F: W_edge normalize ----------------
__global__ __launch_bounds__(256) void wedge_norm(
    const float* __restrict__ We, float* __restrict__ out, int N) {
  int b = blockIdx.x;
  int t = threadIdx.x;
  const float* w = We + (size_t)b * N;
  float ss = 0.f;
  for (int i = t; i < N; i += 256) { float x = w[i]; ss += x * x; }
  for (int off = 32; off; off >>= 1) ss += __shfl_down(ss, off);
  __shared__ float p[4];
  if ((t & 63) == 0) p[t >> 6] = ss;
  __syncthreads();
  float tot = p[0] + p[1] + p[2] + p[3];
  float nrm = fmaxf(sqrtf(tot), 1e-12f);
  for (int i = t; i < N; i += 256) out[(size_t)b * N + i] = w[i] / nrm;
}

extern "C" void kernel_launch(void* const* d_in, const int* in_sizes, int n_in,
                              void* d_out, int out_size, void* d_ws, size_t ws_size,
                              hipStream_t stream) {
  const float* H0 = (const float*)d_in[0];
  const float* vf = (const float*)d_in[1];
  const float* ef = (const float*)d_in[2];
  const float* Wq = (const float*)d_in[3];
  const float* bq = (const float*)d_in[4];
  const float* Wk = (const float*)d_in[5];
  const float* bk = (const float*)d_in[6];
  const int* itp  = (const int*)d_in[7];

  int C = (int)(sqrt((double)in_sizes[3]) + 0.5);          // 128
  long long ratio = (long long)in_sizes[0] / in_sizes[1];  // N/C
  int N = (int)(C * ratio);                                // 2048
  int bs = (int)(in_sizes[1] / ((long long)C * N));        // 8
  size_t bNN = (size_t)bs * N * N;
  size_t bCN = (size_t)bs * C * N;

  float* outH  = (float*)d_out;
  float* outW  = outH + bNN;
  float* outDe = outW + bNN;
  float* outDv = outDe + bNN;
  float* outWe = outDv + bNN;

  // scratch layout: [amin | degE | degV | We | Q | K]
  float* amin = (float*)d_ws;
  float* degE = amin + (size_t)bs * N;
  float* degV = degE + (size_t)bs * N;
  float* We   = degV + (size_t)bs * N;
  size_t small_elems = (size_t)4 * bs * N;
  float* Q;
  float* K;
  if (ws_size >= (small_elems + 2 * bCN) * sizeof(float)) {
    Q = We + (size_t)bs * N;
    K = Q + bCN;
  } else {
    // De/Dv output regions are dead until diag_fill — safe scratch for Q/K.
    Q = outDe;
    K = outDv;
  }

  hipMemsetAsync(degE, 0, (size_t)bs * N * sizeof(float), stream);
  hipMemsetAsync(We, 0, (size_t)bs * N * sizeof(float), stream);

  float sdh = (float)sqrt((double)C);  // NUM_HEADS == 1 -> dh = C

  qk_gemm<<<dim3(N / 128, 2 * bs), 256, 0, stream>>>(Wq, bq, vf, Wk, bk, ef,
                                                     Q, K, C, N, bs);
  att_score<<<dim3(N / 128, N / 128, bs), 256, 0, stream>>>(Q, K, H0, outW,
                                                            C, N, sdh);
  topk_thresh<<<dim3(bs * N), 256, 0, stream>>>(outW, amin, itp, N);
  wh_fused<<<dim3(N / 16, bs), 256, 0, stream>>>(outW, H0, amin, outW, outH,
                                                 degE, degV, We, N);
  int nsh = 0;
  while ((1 << nsh) < N) ++nsh;          // N is a power of two (2048)
  diag_fill<<<dim3(4096, bs), 256, 0, stream>>>(outDe, degE, N, nsh);
  diag_fill<<<dim3(4096, bs), 256, 0, stream>>>(outDv, degV, N, nsh);
  wedge_norm<<<dim3(bs), 256, 0, stream>>>(We, outWe, N);
}

// Round 2
// 1089.929 us; speedup vs baseline: 1.0058x; 1.0058x over previous
//
#include <hip/hip_runtime.h>
#include <math.h>

#define NUM_LAYER 6

// ---------------- Pass A: Q = Wq*vf + bq ; K = Wk*ef + bk ----------------
// C = 128 assumed. 128x128 tile, BK=8, 256 thr, 8x8 micro.
__global__ __launch_bounds__(256) void qk_gemm(
    const float* __restrict__ Wq, const float* __restrict__ bq,
    const float* __restrict__ vf,
    const float* __restrict__ Wk, const float* __restrict__ bk,
    const float* __restrict__ ef,
    float* __restrict__ Qout, float* __restrict__ Kout,
    int C, int N, int bs) {
  int which = (int)blockIdx.y >= bs;
  int b = (int)blockIdx.y - (which ? bs : 0);
  const float* Wm = which ? Wk : Wq;
  const float* bias = which ? bk : bq;
  const float* X = (which ? ef : vf) + (size_t)b * C * N;
  float* P = (which ? Kout : Qout) + (size_t)b * C * N;
  int n0 = blockIdx.x * 128;
  __shared__ float As[8][128];
  __shared__ float Xs[8][128];
  int t = threadIdx.x;
  int tx = t & 15, ty = t >> 4;
  int ao = t >> 1, ac = (t & 1) * 4;
  int lk = t >> 5, lj = (t & 31) * 4;
  float acc[8][8] = {};
  for (int c0 = 0; c0 < C; c0 += 8) {
    __syncthreads();
    float4 wv = *(const float4*)&Wm[(size_t)ao * C + c0 + ac];
    As[ac + 0][ao] = wv.x; As[ac + 1][ao] = wv.y;
    As[ac + 2][ao] = wv.z; As[ac + 3][ao] = wv.w;
    *(float4*)&Xs[lk][lj] = *(const float4*)&X[(size_t)(c0 + lk) * N + n0 + lj];
    __syncthreads();
#pragma unroll
    for (int kk = 0; kk < 8; ++kk) {
      float a[8], bb[8];
      *(float4*)&a[0]  = *(const float4*)&As[kk][ty * 4];
      *(float4*)&a[4]  = *(const float4*)&As[kk][64 + ty * 4];
      *(float4*)&bb[0] = *(const float4*)&Xs[kk][tx * 4];
      *(float4*)&bb[4] = *(const float4*)&Xs[kk][64 + tx * 4];
#pragma unroll
      for (int i = 0; i < 8; ++i)
#pragma unroll
        for (int j = 0; j < 8; ++j)
          acc[i][j] = fmaf(a[i], bb[j], acc[i][j]);
    }
  }
#pragma unroll
  for (int i = 0; i < 8; ++i) {
    int row = (i >> 2) * 64 + ty * 4 + (i & 3);
    float bv = bias[row];
    float4 o0 = { acc[i][0] + bv, acc[i][1] + bv, acc[i][2] + bv, acc[i][3] + bv };
    float4 o1 = { acc[i][4] + bv, acc[i][5] + bv, acc[i][6] + bv, acc[i][7] + bv };
    *(float4*)&P[(size_t)row * N + n0 + tx * 4] = o0;
    *(float4*)&P[(size_t)row * N + n0 + 64 + tx * 4] = o1;
  }
}

// ---------------- Pass B: score = sigmoid(Q^T K / sqrt(dh)) masked ----------------
__global__ __launch_bounds__(256) void att_score(
    const float* __restrict__ Q, const float* __restrict__ K,
    const float* __restrict__ H0, float* __restrict__ score,
    int C, int N, float rsdh) {
  int b = blockIdx.z;
  int o0 = blockIdx.y * 128, i0 = blockIdx.x * 128;
  const float* Qb = Q + (size_t)b * C * N;
  const float* Kb = K + (size_t)b * C * N;
  const float* Hb = H0 + (size_t)b * N * N;
  float* Sb = score + (size_t)b * N * N;
  __shared__ float As[8][128];
  __shared__ float Bs[8][128];
  int t = threadIdx.x;
  int tx = t & 15, ty = t >> 4;
  int lk = t >> 5, lj = (t & 31) * 4;
  float acc[8][8] = {};
  for (int c0 = 0; c0 < C; c0 += 8) {
    __syncthreads();
    *(float4*)&As[lk][lj] = *(const float4*)&Qb[(size_t)(c0 + lk) * N + o0 + lj];
    *(float4*)&Bs[lk][lj] = *(const float4*)&Kb[(size_t)(c0 + lk) * N + i0 + lj];
    __syncthreads();
#pragma unroll
    for (int kk = 0; kk < 8; ++kk) {
      float a[8], bb[8];
      *(float4*)&a[0]  = *(const float4*)&As[kk][ty * 4];
      *(float4*)&a[4]  = *(const float4*)&As[kk][64 + ty * 4];
      *(float4*)&bb[0] = *(const float4*)&Bs[kk][tx * 4];
      *(float4*)&bb[4] = *(const float4*)&Bs[kk][64 + tx * 4];
#pragma unroll
      for (int i = 0; i < 8; ++i)
#pragma unroll
        for (int j = 0; j < 8; ++j)
          acc[i][j] = fmaf(a[i], bb[j], acc[i][j]);
    }
  }
#pragma unroll
  for (int i = 0; i < 8; ++i) {
    int row = o0 + (i >> 2) * 64 + ty * 4 + (i & 3);
    size_t base = (size_t)row * N + i0;
#pragma unroll
    for (int g = 0; g < 2; ++g) {
      size_t off = base + g * 64 + tx * 4;
      float4 h = *(const float4*)&Hb[off];
      float4 o;
      o.x = (h.x > 0.f) ? 1.f / (1.f + __expf(-acc[i][g*4+0] * rsdh)) : 0.f;
      o.y = (h.y > 0.f) ? 1.f / (1.f + __expf(-acc[i][g*4+1] * rsdh)) : 0.f;
      o.z = (h.z > 0.f) ? 1.f / (1.f + __expf(-acc[i][g*4+2] * rsdh)) : 0.f;
      o.w = (h.w > 0.f) ? 1.f / (1.f + __expf(-acc[i][g*4+3] * rsdh)) : 0.f;
      *(float4*)&Sb[off] = o;
    }
  }
}

// ---- Pass C (fused): per-row exact k-th largest (wave-local bitwise binary
// search, no barriers) + select W/H + degV + column partials (no atomics) ----
// grid: (N/16, bs); block 1024 = 16 waves; wave w owns row strip*16+w.
__global__ __launch_bounds__(1024) void select_wh(
    const float* __restrict__ H0, float* __restrict__ scoreW /* in: score, out: W */,
    float* __restrict__ Hout, float* __restrict__ degV,
    float* __restrict__ PE, float* __restrict__ PW,
    const int* __restrict__ itp, int N) {
  int b = blockIdx.y;
  int strip = blockIdx.x;
  int r0 = strip * 16;
  int t = threadIdx.x;
  int wave = t >> 6, lane = t & 63;
  size_t bNN = (size_t)b * N * N;
  __shared__ float aminS[16];
  __shared__ float dpart[16][16];  // [wave][row]

  // ---- phase 1: one wave per row, in-register binary search ----
  {
    int row = r0 + wave;
    const float* srow = scoreW + bNN + (size_t)row * N;
    int nq = N >> 6;  // 32 at N=2048
    float v[32];
    for (int q = 0; q < nq; ++q) v[q] = srow[lane + (q << 6)];
    int itv = *itp;
    int k = (int)floor((double)N * 0.1 * (double)(NUM_LAYER - 1 - itv) + 0.5);
    unsigned lo = 0u, hi = 0x3F800000u;  // scores in [0, 1]
    while (lo < hi) {
      unsigned mid = lo + ((hi - lo + 1u) >> 1);
      float thr = __uint_as_float(mid);
      int c = 0;
      for (int q = 0; q < nq; ++q) c += (v[q] >= thr) ? 1 : 0;
      for (int off = 1; off < 64; off <<= 1) c += __shfl_xor(c, off);
      if (c >= k) lo = mid; else hi = mid - 1u;
    }
    if (lane == 0) aminS[wave] = __uint_as_float(lo);
  }
  __syncthreads();

  // ---- phase 2: thread t streams cols {2t, 2t+1} down the 16 rows ----
  float accE0 = 0.f, accE1 = 0.f, accW0 = 0.f, accW1 = 0.f;
  float dv[16];
#pragma unroll
  for (int r = 0; r < 16; ++r) {
    float am = aminS[r];
    size_t off = bNN + (size_t)(r0 + r) * N + 2 * t;
    float2 s  = *(const float2*)(scoreW + off);
    float2 h0 = *(const float2*)(H0 + off);
    float2 w, h;
    w.x = (s.x >= am) ? s.x : 0.f; h.x = (w.x > 0.f) ? h0.x : 0.f;
    w.y = (s.y >= am) ? s.y : 0.f; h.y = (w.y > 0.f) ? h0.y : 0.f;
    *(float2*)(scoreW + off) = w;
    *(float2*)(Hout + off) = h;
    accW0 += w.x; accW1 += w.y;
    accE0 += h.x; accE1 += h.y;
    dv[r] = h.x + h.y;
  }
  // block-reduce dv per row
#pragma unroll
  for (int r = 0; r < 16; ++r) {
    float x = dv[r];
    for (int off = 32; off; off >>= 1) x += __shfl_down(x, off);
    if (lane == 0) dpart[wave][r] = x;
  }
  __syncthreads();
  if (t < 16) {
    float s = 0.f;
#pragma unroll
    for (int w = 0; w < 16; ++w) s += dpart[w][t];
    degV[b * N + r0 + t] = s;
  }
  // column partials (non-atomic)
  int S = N >> 4;
  size_t pbase = ((size_t)b * S + strip) * N + 2 * t;
  float2 pe = {accE0, accE1}, pw = {accW0, accW1};
  *(float2*)(PE + pbase) = pe;
  *(float2*)(PW + pbase) = pw;
}

// ---------------- Pass D: reduce column partials -> degE, We ----------------
__global__ __launch_bounds__(256) void col_reduce(
    const float* __restrict__ PE, const float* __restrict__ PW,
    float* __restrict__ degE, float* __restrict__ We, int N) {
  int b = blockIdx.y;
  int col = blockIdx.x * 256 + threadIdx.x;
  int S = N >> 4;
  float se = 0.f, sw = 0.f;
  for (int s = 0; s < S; ++s) {
    size_t off = ((size_t)b * S + s) * N + col;
    se += PE[off];
    sw += PW[off];
  }
  degE[b * N + col] = se;
  We[b * N + col] = sw;
}

// ---------------- Pass E: write diagonals (regions pre-zeroed by memset) ----
__global__ __launch_bounds__(256) void diag_write(
    float* __restrict__ De, float* __restrict__ Dv,
    const float* __restrict__ degE, const float* __restrict__ degV, int N) {
  int idx = blockIdx.x * 256 + threadIdx.x;  // bs*N total
  int b = idx / N, i = idx - b * N;
  size_t d = (size_t)b * N * N + (size_t)i * N + i;
  float e = degE[idx], v = degV[idx];
  De[d] = (e != 0.f) ? 1.f / e : 0.f;
  Dv[d] = (v != 0.f) ? 1.f / v : 0.f;
}

// ---------------- Pass F: W_edge normalize ----------------
__global__ __launch_bounds__(256) void wedge_norm(
    const float* __restrict__ We, float* __restrict__ out, int N) {
  int b = blockIdx.x;
  int t = threadIdx.x;
  const float* w = We + (size_t)b * N;
  float ss = 0.f;
  for (int i = t; i < N; i += 256) { float x = w[i]; ss += x * x; }
  for (int off = 32; off; off >>= 1) ss += __shfl_down(ss, off);
  __shared__ float p[4];
  if ((t & 63) == 0) p[t >> 6] = ss;
  __syncthreads();
  float tot = p[0] + p[1] + p[2] + p[3];
  float nrm = fmaxf(sqrtf(tot), 1e-12f);
  for (int i = t; i < N; i += 256) out[(size_t)b * N + i] = w[i] / nrm;
}

extern "C" void kernel_launch(void* const* d_in, const int* in_sizes, int n_in,
                              void* d_out, int out_size, void* d_ws, size_t ws_size,
                              hipStream_t stream) {
  const float* H0 = (const float*)d_in[0];
  const float* vf = (const float*)d_in[1];
  const float* ef = (const float*)d_in[2];
  const float* Wq = (const float*)d_in[3];
  const float* bq = (const float*)d_in[4];
  const float* Wk = (const float*)d_in[5];
  const float* bk = (const float*)d_in[6];
  const int* itp  = (const int*)d_in[7];

  int C = (int)(sqrt((double)in_sizes[3]) + 0.5);          // 128
  long long ratio = (long long)in_sizes[0] / in_sizes[1];  // N/C
  int N = (int)(C * ratio);                                // 2048
  int bs = (int)(in_sizes[1] / ((long long)C * N));        // 8
  size_t bNN = (size_t)bs * N * N;
  size_t bCN = (size_t)bs * C * N;
  int S = N >> 4;                                          // strips per batch
  size_t pElems = (size_t)bs * S * N;                      // partial array elems

  float* outH  = (float*)d_out;
  float* outW  = outH + bNN;
  float* outDe = outW + bNN;
  float* outDv = outDe + bNN;
  float* outWe = outDv + bNN;

  // scratch layout: [degE | degV | We | Q | K | PE | PW]
  size_t bsN = (size_t)bs * N;
  float* degE = (float*)d_ws;
  float* degV = degE + bsN;
  float* We   = degV + bsN;
  float* Q;
  float* K;
  float* PE;
  float* PW;
  size_t need = (3 * bsN + 2 * bCN + 2 * pElems) * sizeof(float);
  if (ws_size >= need) {
    Q  = We + bsN;
    K  = Q + bCN;
    PE = K + bCN;
    PW = PE + pElems;
  } else {
    // outDe/outDv are dead until the memset below — safe scratch.
    Q  = outDe;
    K  = Q + bCN;
    PE = outDv;
    PW = PE + pElems;
  }

  float rsdh = (float)(1.0 / sqrt((double)C));  // NUM_HEADS==1 -> dh=C

  qk_gemm<<<dim3(N / 128, 2 * bs), 256, 0, stream>>>(Wq, bq, vf, Wk, bk, ef,
                                                     Q, K, C, N, bs);
  att_score<<<dim3(N / 128, N / 128, bs), 256, 0, stream>>>(Q, K, H0, outW,
                                                            C, N, rsdh);
  select_wh<<<dim3(S, bs), 1024, 0, stream>>>(H0, outW, outH, degV, PE, PW,
                                              itp, N);
  col_reduce<<<dim3(N / 256, bs), 256, 0, stream>>>(PE, PW, degE, We, N);
  // zero De+Dv (contiguous), then write diagonals
  hipMemsetAsync(outDe, 0, 2 * bNN * sizeof(float), stream);
  diag_write<<<dim3((bs * N) / 256), 256, 0, stream>>>(outDe, outDv, degE,
                                                       degV, N);
  wedge_norm<<<dim3(bs), 256, 0, stream>>>(We, outWe, N);
}

// Round 3
// 936.424 us; speedup vs baseline: 1.1707x; 1.1639x over previous
//
#include <hip/hip_runtime.h>
#include <math.h>

#define NUM_LAYER 6

// ---------------- Pass A: Q = Wq*vf + bq ; K = Wk*ef + bk ----------------
// C = 128 assumed. 128x128 tile, BK=8, 256 thr, 8x8 micro.
__global__ __launch_bounds__(256) void qk_gemm(
    const float* __restrict__ Wq, const float* __restrict__ bq,
    const float* __restrict__ vf,
    const float* __restrict__ Wk, const float* __restrict__ bk,
    const float* __restrict__ ef,
    float* __restrict__ Qout, float* __restrict__ Kout,
    int C, int N, int bs) {
  int which = (int)blockIdx.y >= bs;
  int b = (int)blockIdx.y - (which ? bs : 0);
  const float* Wm = which ? Wk : Wq;
  const float* bias = which ? bk : bq;
  const float* X = (which ? ef : vf) + (size_t)b * C * N;
  float* P = (which ? Kout : Qout) + (size_t)b * C * N;
  int n0 = blockIdx.x * 128;
  __shared__ float As[8][128];
  __shared__ float Xs[8][128];
  int t = threadIdx.x;
  int tx = t & 15, ty = t >> 4;
  int ao = t >> 1, ac = (t & 1) * 4;
  int lk = t >> 5, lj = (t & 31) * 4;
  float acc[8][8] = {};
  for (int c0 = 0; c0 < C; c0 += 8) {
    __syncthreads();
    float4 wv = *(const float4*)&Wm[(size_t)ao * C + c0 + ac];
    As[ac + 0][ao] = wv.x; As[ac + 1][ao] = wv.y;
    As[ac + 2][ao] = wv.z; As[ac + 3][ao] = wv.w;
    *(float4*)&Xs[lk][lj] = *(const float4*)&X[(size_t)(c0 + lk) * N + n0 + lj];
    __syncthreads();
#pragma unroll
    for (int kk = 0; kk < 8; ++kk) {
      float a[8], bb[8];
      *(float4*)&a[0]  = *(const float4*)&As[kk][ty * 4];
      *(float4*)&a[4]  = *(const float4*)&As[kk][64 + ty * 4];
      *(float4*)&bb[0] = *(const float4*)&Xs[kk][tx * 4];
      *(float4*)&bb[4] = *(const float4*)&Xs[kk][64 + tx * 4];
#pragma unroll
      for (int i = 0; i < 8; ++i)
#pragma unroll
        for (int j = 0; j < 8; ++j)
          acc[i][j] = fmaf(a[i], bb[j], acc[i][j]);
    }
  }
#pragma unroll
  for (int i = 0; i < 8; ++i) {
    int row = (i >> 2) * 64 + ty * 4 + (i & 3);
    float bv = bias[row];
    float4 o0 = { acc[i][0] + bv, acc[i][1] + bv, acc[i][2] + bv, acc[i][3] + bv };
    float4 o1 = { acc[i][4] + bv, acc[i][5] + bv, acc[i][6] + bv, acc[i][7] + bv };
    *(float4*)&P[(size_t)row * N + n0 + tx * 4] = o0;
    *(float4*)&P[(size_t)row * N + n0 + 64 + tx * 4] = o1;
  }
}

// ---------------- Pass B: score = sigmoid(Q^T K / sqrt(dh)) masked ----------------
__global__ __launch_bounds__(256) void att_score(
    const float* __restrict__ Q, const float* __restrict__ K,
    const float* __restrict__ H0, float* __restrict__ score,
    int C, int N, float rsdh) {
  int b = blockIdx.z;
  int o0 = blockIdx.y * 128, i0 = blockIdx.x * 128;
  const float* Qb = Q + (size_t)b * C * N;
  const float* Kb = K + (size_t)b * C * N;
  const float* Hb = H0 + (size_t)b * N * N;
  float* Sb = score + (size_t)b * N * N;
  __shared__ float As[8][128];
  __shared__ float Bs[8][128];
  int t = threadIdx.x;
  int tx = t & 15, ty = t >> 4;
  int lk = t >> 5, lj = (t & 31) * 4;
  float acc[8][8] = {};
  for (int c0 = 0; c0 < C; c0 += 8) {
    __syncthreads();
    *(float4*)&As[lk][lj] = *(const float4*)&Qb[(size_t)(c0 + lk) * N + o0 + lj];
    *(float4*)&Bs[lk][lj] = *(const float4*)&Kb[(size_t)(c0 + lk) * N + i0 + lj];
    __syncthreads();
#pragma unroll
    for (int kk = 0; kk < 8; ++kk) {
      float a[8], bb[8];
      *(float4*)&a[0]  = *(const float4*)&As[kk][ty * 4];
      *(float4*)&a[4]  = *(const float4*)&As[kk][64 + ty * 4];
      *(float4*)&bb[0] = *(const float4*)&Bs[kk][tx * 4];
      *(float4*)&bb[4] = *(const float4*)&Bs[kk][64 + tx * 4];
#pragma unroll
      for (int i = 0; i < 8; ++i)
#pragma unroll
        for (int j = 0; j < 8; ++j)
          acc[i][j] = fmaf(a[i], bb[j], acc[i][j]);
    }
  }
#pragma unroll
  for (int i = 0; i < 8; ++i) {
    int row = o0 + (i >> 2) * 64 + ty * 4 + (i & 3);
    size_t base = (size_t)row * N + i0;
#pragma unroll
    for (int g = 0; g < 2; ++g) {
      size_t off = base + g * 64 + tx * 4;
      float4 h = *(const float4*)&Hb[off];
      float4 o;
      o.x = (h.x > 0.f) ? 1.f / (1.f + __expf(-acc[i][g*4+0] * rsdh)) : 0.f;
      o.y = (h.y > 0.f) ? 1.f / (1.f + __expf(-acc[i][g*4+1] * rsdh)) : 0.f;
      o.z = (h.z > 0.f) ? 1.f / (1.f + __expf(-acc[i][g*4+2] * rsdh)) : 0.f;
      o.w = (h.w > 0.f) ? 1.f / (1.f + __expf(-acc[i][g*4+3] * rsdh)) : 0.f;
      *(float4*)&Sb[off] = o;
    }
  }
}

// ---- Pass C (fused): per-row exact k-th largest + select W/H + degV +
// column partials. NQ = N/64 is compile-time so v[] stays in VGPRs.
// grid: (N/8, bs); block 512 = 8 waves; wave w owns row strip*8+w in phase 1.
template <int NQ>
__global__ __launch_bounds__(512) void select_wh_t(
    const float* __restrict__ H0, float* __restrict__ scoreW,
    float* __restrict__ Hout, float* __restrict__ degV,
    float* __restrict__ PE, float* __restrict__ PW,
    const int* __restrict__ itp, int N) {
  int b = blockIdx.y;
  int strip = blockIdx.x;
  int r0 = strip * 8;
  int t = threadIdx.x;
  int wave = t >> 6, lane = t & 63;
  size_t bNN = (size_t)b * N * N;
  __shared__ float aminS[8];
  __shared__ float dpart[8][8];  // [wave][row]

  // ---- phase 1: one wave per row, register-resident binary search ----
  {
    int row = r0 + wave;
    const float* srow = scoreW + bNN + (size_t)row * N;
    float v[NQ];
#pragma unroll
    for (int q = 0; q < NQ; ++q) v[q] = srow[lane + (q << 6)];
    int itv = *itp;
    int k = (int)floor((double)N * 0.1 * (double)(NUM_LAYER - 1 - itv) + 0.5);
    unsigned lo = 0u, hi = 0x3F800000u;  // scores in [0, 1]
    while (lo < hi) {
      unsigned mid = lo + ((hi - lo + 1u) >> 1);
      float thr = __uint_as_float(mid);
      int c = 0;
#pragma unroll
      for (int q = 0; q < NQ; ++q) c += (v[q] >= thr) ? 1 : 0;
#pragma unroll
      for (int off = 1; off < 64; off <<= 1) c += __shfl_xor(c, off);
      if (c >= k) lo = mid; else hi = mid - 1u;
    }
    if (lane == 0) aminS[wave] = __uint_as_float(lo);
  }
  __syncthreads();

  // ---- phase 2: thread t streams cols 4t..4t+3 down the 8 rows ----
  float4 accE = {0.f, 0.f, 0.f, 0.f};
  float4 accW = {0.f, 0.f, 0.f, 0.f};
  float dv[8];
#pragma unroll
  for (int r = 0; r < 8; ++r) {
    float am = aminS[r];
    size_t off = bNN + (size_t)(r0 + r) * N + 4 * t;
    float4 s  = *(const float4*)(scoreW + off);
    float4 h0 = *(const float4*)(H0 + off);
    float4 w, h;
    w.x = (s.x >= am) ? s.x : 0.f; h.x = (w.x > 0.f) ? h0.x : 0.f;
    w.y = (s.y >= am) ? s.y : 0.f; h.y = (w.y > 0.f) ? h0.y : 0.f;
    w.z = (s.z >= am) ? s.z : 0.f; h.z = (w.z > 0.f) ? h0.z : 0.f;
    w.w = (s.w >= am) ? s.w : 0.f; h.w = (w.w > 0.f) ? h0.w : 0.f;
    *(float4*)(scoreW + off) = w;
    *(float4*)(Hout + off) = h;
    accW.x += w.x; accW.y += w.y; accW.z += w.z; accW.w += w.w;
    accE.x += h.x; accE.y += h.y; accE.z += h.z; accE.w += h.w;
    dv[r] = h.x + h.y + h.z + h.w;
  }
#pragma unroll
  for (int r = 0; r < 8; ++r) {
    float x = dv[r];
#pragma unroll
    for (int off = 32; off; off >>= 1) x += __shfl_down(x, off);
    if (lane == 0) dpart[wave][r] = x;
  }
  __syncthreads();
  if (t < 8) {
    float s = 0.f;
#pragma unroll
    for (int w = 0; w < 8; ++w) s += dpart[w][t];
    degV[b * N + r0 + t] = s;
  }
  int S = N >> 3;
  size_t pbase = ((size_t)b * S + strip) * N + 4 * t;
  *(float4*)(PE + pbase) = accE;
  *(float4*)(PW + pbase) = accW;
}

// ---------------- Pass D: reduce column partials -> degE, We ----------------
__global__ __launch_bounds__(256) void col_reduce(
    const float* __restrict__ PE, const float* __restrict__ PW,
    float* __restrict__ degE, float* __restrict__ We, int N, int S) {
  int b = blockIdx.y;
  int col = blockIdx.x * 256 + threadIdx.x;
  float se = 0.f, sw = 0.f;
  for (int s = 0; s < S; ++s) {
    size_t off = ((size_t)b * S + s) * N + col;
    se += PE[off];
    sw += PW[off];
  }
  degE[b * N + col] = se;
  We[b * N + col] = sw;
}

// ---------------- Pass E: write diagonals (regions pre-zeroed by memset) ----
__global__ __launch_bounds__(256) void diag_write(
    float* __restrict__ De, float* __restrict__ Dv,
    const float* __restrict__ degE, const float* __restrict__ degV, int N) {
  int idx = blockIdx.x * 256 + threadIdx.x;  // bs*N total
  int b = idx / N, i = idx - b * N;
  size_t d = (size_t)b * N * N + (size_t)i * N + i;
  float e = degE[idx], v = degV[idx];
  De[d] = (e != 0.f) ? 1.f / e : 0.f;
  Dv[d] = (v != 0.f) ? 1.f / v : 0.f;
}

// ---------------- Pass F: W_edge normalize ----------------
__global__ __launch_bounds__(256) void wedge_norm(
    const float* __restrict__ We, float* __restrict__ out, int N) {
  int b = blockIdx.x;
  int t = threadIdx.x;
  const float* w = We + (size_t)b * N;
  float ss = 0.f;
  for (int i = t; i < N; i += 256) { float x = w[i]; ss += x * x; }
  for (int off = 32; off; off >>= 1) ss += __shfl_down(ss, off);
  __shared__ float p[4];
  if ((t & 63) == 0) p[t >> 6] = ss;
  __syncthreads();
  float tot = p[0] + p[1] + p[2] + p[3];
  float nrm = fmaxf(sqrtf(tot), 1e-12f);
  for (int i = t; i < N; i += 256) out[(size_t)b * N + i] = w[i] / nrm;
}

extern "C" void kernel_launch(void* const* d_in, const int* in_sizes, int n_in,
                              void* d_out, int out_size, void* d_ws, size_t ws_size,
                              hipStream_t stream) {
  const float* H0 = (const float*)d_in[0];
  const float* vf = (const float*)d_in[1];
  const float* ef = (const float*)d_in[2];
  const float* Wq = (const float*)d_in[3];
  const float* bq = (const float*)d_in[4];
  const float* Wk = (const float*)d_in[5];
  const float* bk = (const float*)d_in[6];
  const int* itp  = (const int*)d_in[7];

  int C = (int)(sqrt((double)in_sizes[3]) + 0.5);          // 128
  long long ratio = (long long)in_sizes[0] / in_sizes[1];  // N/C
  int N = (int)(C * ratio);                                // 2048
  int bs = (int)(in_sizes[1] / ((long long)C * N));        // 8
  size_t bNN = (size_t)bs * N * N;
  size_t bCN = (size_t)bs * C * N;
  int S = N >> 3;                                          // strips of 8 rows
  size_t pElems = (size_t)bs * S * N;

  float* outH  = (float*)d_out;
  float* outW  = outH + bNN;
  float* outDe = outW + bNN;
  float* outDv = outDe + bNN;
  float* outWe = outDv + bNN;

  // scratch layout: [degE | degV | We | Q | K | PE | PW]
  size_t bsN = (size_t)bs * N;
  float* degE = (float*)d_ws;
  float* degV = degE + bsN;
  float* We   = degV + bsN;
  float* Q;
  float* K;
  float* PE;
  float* PW;
  size_t need = (3 * bsN + 2 * bCN + 2 * pElems) * sizeof(float);
  if (ws_size >= need) {
    Q  = We + bsN;
    K  = Q + bCN;
    PE = K + bCN;
    PW = PE + pElems;
  } else {
    // outDe/outDv are dead until the memset below — safe scratch.
    Q  = outDe;
    K  = Q + bCN;
    PE = outDv;
    PW = PE + pElems;
  }

  float rsdh = (float)(1.0 / sqrt((double)C));  // NUM_HEADS==1 -> dh=C

  qk_gemm<<<dim3(N / 128, 2 * bs), 256, 0, stream>>>(Wq, bq, vf, Wk, bk, ef,
                                                     Q, K, C, N, bs);
  att_score<<<dim3(N / 128, N / 128, bs), 256, 0, stream>>>(Q, K, H0, outW,
                                                            C, N, rsdh);
  if (N == 2048)
    select_wh_t<32><<<dim3(S, bs), 512, 0, stream>>>(H0, outW, outH, degV,
                                                     PE, PW, itp, N);
  else if (N == 1024)
    select_wh_t<16><<<dim3(S, bs), 512, 0, stream>>>(H0, outW, outH, degV,
                                                     PE, PW, itp, N);
  else
    select_wh_t<64><<<dim3(S, bs), 512, 0, stream>>>(H0, outW, outH, degV,
                                                     PE, PW, itp, N);  // N==4096
  col_reduce<<<dim3(N / 256, bs), 256, 0, stream>>>(PE, PW, degE, We, N, S);
  hipMemsetAsync(outDe, 0, 2 * bNN * sizeof(float), stream);
  diag_write<<<dim3((bs * N) / 256), 256, 0, stream>>>(outDe, outDv, degE,
                                                       degV, N);
  wedge_norm<<<dim3(bs), 256, 0, stream>>>(We, outWe, N);
}